// Round 2
// baseline (160.060 us; speedup 1.0000x reference)
//
#include <hip/hip_runtime.h>

// Batched Thomas solve, B=2048 rows, N=8192, fp32.
// One block per row; TB=1024 threads x CH=8-element contiguous chunks.
//
// R6 vs R5 (post-mortem: R5 spilled exactly one CH=8 array to scratch --
// WRITE_SIZE 64->128 MiB, FETCH +30 MiB, VALUBusy 65->41% on vmcnt stalls;
// launch_bounds(1024,8) caps us at 64 unified regs/wave and R5's peak live
// set (va,vf,cpv,asv,bsv + dpv + uv) exceeded it):
//  1) Drop asv[]/bsv[]: store ONE array rd[k] = z_{k-1}*rcp(z_k) (the Thomas
//     denominator reciprocal). dp chunk totals need only the sweep's final
//     state: Ad = prod(-a_i)*rcp(z_CH), Bd = y_CH*rcp(z_CH).
//  2) After the dp wave-scan yields dp_in, a short serial resweep
//     dp_k = (f_k - a_k*dp_{k-1})*rd_k materializes dpv IN PLACE over rd[]
//     (rd_k's last use is the step producing dp_k). The final back-sub
//     overwrites the same array again before the float4 stores.
//  Peak live set: va[8]+vf[8]+cpv[8]+drv[8] = 32 floats + ~10 scalars < 64.

#define NN 8192
#define TB 1024
#define CH 8           // NN / TB
#define NWAVE (TB/64)  // 16

__device__ __forceinline__ float frcp(float x) { return __builtin_amdgcn_rcpf(x); }

__global__ __launch_bounds__(TB, 8)
void thomas_scan_kernel(const float* __restrict__ alpha,
                        const float* __restrict__ fvec,
                        float* __restrict__ out)
{
    __shared__ __align__(16) float wtot[NWAVE][4];  // cp 2x2 wave totals (p,q,u,v)
    __shared__ __align__(8)  float dtot[NWAVE][2];  // dp affine wave totals (A,B)
    __shared__ __align__(8)  float btot[NWAVE][2];  // backward affine wave totals

    const int t    = threadIdx.x;
    const int lane = t & 63;
    const int wid  = t >> 6;
    const int row  = blockIdx.x;
    const float* __restrict__ arow = alpha + (size_t)row * NN;
    const int base = t * CH;

    // ---- load alpha chunk + halo, f chunk into registers ----
    float va[CH], vf[CH];
    {
        const float4* a4 = reinterpret_cast<const float4*>(arow + base);
        const float4* f4 = reinterpret_cast<const float4*>(fvec + base);
        #pragma unroll
        for (int k = 0; k < CH / 4; ++k) {
            float4 x = a4[k];
            va[4*k+0]=x.x; va[4*k+1]=x.y; va[4*k+2]=x.z; va[4*k+3]=x.w;
            float4 y = f4[k];
            vf[4*k+0]=y.x; vf[4*k+1]=y.y; vf[4*k+2]=y.z; vf[4*k+3]=y.w;
        }
    }
    const float aL = (t > 0)      ? arow[base - 1]  : 0.0f;  // => a_0 = 0
    const float aR = (t < TB - 1) ? arow[base + CH] : 0.0f;  // => c_{N-1} = 0

    // ---- Phase A: 2x2 cp chunk map [[p,q],[u,v]] on homogeneous (x,z) ----
    float p=1.f, q=0.f, u=0.f, v=1.f;
    #pragma unroll
    for (int k = 0; k < CH; ++k) {
        const float am1 = (k == 0)      ? aL : va[k-1];
        const float ap1 = (k == CH - 1) ? aR : va[k+1];
        const float ai = am1 * am1;
        const float bi = 1.0f + va[k]*va[k]*va[k];
        const float ci = ap1 * (ap1 + 2.0f);
        const float np = ci*u,        nq = ci*v;
        const float nu = bi*u - ai*p, nv = bi*v - ai*q;
        p=np; q=nq; u=nu; v=nv;
    }
    { const float inv = frcp(v); p*=inv; q*=inv; u*=inv; v=1.0f; }

    // ---- forward wave-inclusive shuffle scan (2x2 matmul compose) ----
    #pragma unroll
    for (int off = 1; off < 64; off <<= 1) {
        const float p1=__shfl_up(p,off), q1=__shfl_up(q,off),
                    u1=__shfl_up(u,off), v1=__shfl_up(v,off);
        if (lane >= off) {
            const float np = p*p1 + q*u1, nq = p*q1 + q*v1;
            const float nu = u*p1 + v*u1, nv = u*q1 + v*v1;
            p=np; q=nq; u=nu; v=nv;
        }
    }
    if (lane == 63) { wtot[wid][0]=p; wtot[wid][1]=q; wtot[wid][2]=u; wtot[wid][3]=v; }
    __syncthreads();

    // exclusive-within-wave map
    float ep=__shfl_up(p,1), eq=__shfl_up(q,1), eu=__shfl_up(u,1), ev=__shfl_up(v,1);
    if (lane == 0) { ep=1.f; eq=0.f; eu=0.f; ev=1.f; }

    // prefix over previous waves, COLUMN form: state = T_{w-1}..T_0 * (0,1)^T
    float Pq = 0.f, Pv = 1.f;
    for (int w = 0; w < wid; ++w) {
        const float4 T = *reinterpret_cast<const float4*>(wtot[w]);
        const float nq = T.x*Pq + T.y*Pv;
        const float nv = T.z*Pq + T.w*Pv;
        Pq = nq; Pv = nv;
    }
    float cp;
    {
        const float nx = ep*Pq + eq*Pv;
        const float nz = eu*Pq + ev*Pv;
        cp = nx * frcp(nz);
    }

    // ---- Phase C: homogeneous forward sweep; store cpv + rd only ----
    // x_k = c_k z_{k-1}; z_k = b_k z_{k-1} - a_k x_{k-1};
    // y_k = f_k z_{k-1} - a_k y_{k-1};  rd_k = z_{k-1}/z_k = 1/(b_k - a_k cp_{k-1})
    float cpv[CH], drv[CH];   // drv holds rd now; dpv later; u values at the end
    float alp = 1.0f;         // prod(-a_i)
    {
        float xp = cp, zp = 1.0f, yb = 0.0f;
        #pragma unroll
        for (int k = 0; k < CH; ++k) {
            const float am1 = (k == 0)      ? aL : va[k-1];
            const float ap1 = (k == CH - 1) ? aR : va[k+1];
            const float ai = am1 * am1;
            const float bi = 1.0f + va[k]*va[k]*va[k];
            const float ci = ap1 * (ap1 + 2.0f);
            const float x = ci * zp;
            const float z = bi*zp - ai*xp;
            const float y = vf[k]*zp - ai*yb;
            const float rdz = frcp(z);
            cpv[k] = x  * rdz;
            drv[k] = zp * rdz;
            alp = -ai * alp;
            xp = x; zp = z; yb = y;
        }
        // dp chunk affine map from final sweep state only
        const float rdzL = frcp(zp);
        alp = alp * rdzL;     // Ad
        yb  = yb  * rdzL;     // Bd
        // stash in p/q names to keep scalar count low
        p = alp; q = yb;
    }

    // ---- dp affine wave scan: chunk map dp_out = Ad*dp_in + Bd ----
    float Ad = p, Bd = q;
    #pragma unroll
    for (int off = 1; off < 64; off <<= 1) {
        const float A1 = __shfl_up(Ad, off);
        const float B1 = __shfl_up(Bd, off);
        if (lane >= off) { Bd = Ad*B1 + Bd; Ad = Ad*A1; }
    }
    if (lane == 63) { dtot[wid][0]=Ad; dtot[wid][1]=Bd; }
    __syncthreads();

    float eAd = __shfl_up(Ad,1), eBd = __shfl_up(Bd,1);
    if (lane == 0) { eAd = 1.0f; eBd = 0.0f; }
    float PB = 0.f;  // prefix applied to dp_0 = 0: only B needed
    for (int w = 0; w < wid; ++w) {
        const float2 T = *reinterpret_cast<const float2*>(dtot[w]);
        PB = T.x*PB + T.y;
    }
    const float dp_in = eAd*PB + eBd;

    // ---- dp resweep IN PLACE over drv (rd_k read, dp_k written) ----
    {
        float dp = dp_in;
        #pragma unroll
        for (int k = 0; k < CH; ++k) {
            const float am1 = (k == 0) ? aL : va[k-1];
            const float ai  = am1 * am1;
            dp = (vf[k] - ai*dp) * drv[k];
            drv[k] = dp;
        }
    }
    // va, vf dead from here.

    // ---- Phase D: backward affine chunk map u_left = A*u_right + B ----
    float A = 1.0f, Bb = 0.0f;
    #pragma unroll
    for (int k = CH - 1; k >= 0; --k) {
        Bb = drv[k] - cpv[k]*Bb;
        A  = -cpv[k]*A;
    }
    // wave-inclusive suffix scan: comp(mine, later): B = A*B1 + B, A = A*A1
    #pragma unroll
    for (int off = 1; off < 64; off <<= 1) {
        const float A1 = __shfl_down(A, off);
        const float B1 = __shfl_down(Bb, off);
        if (lane < 64 - off) { Bb = A*B1 + Bb; A = A*A1; }
    }
    if (lane == 0) { btot[wid][0] = A; btot[wid][1] = Bb; }
    __syncthreads();

    // exclusive-within-wave suffix
    float eA = __shfl_down(A, 1), eB = __shfl_down(Bb, 1);
    if (lane == 63) { eA = 1.0f; eB = 0.0f; }
    // suffix over later waves applied to u_N = 0: only B needed
    float SB = 0.f;
    for (int w = NWAVE - 1; w > wid; --w) {
        const float2 T = *reinterpret_cast<const float2*>(btot[w]);
        SB = T.x*SB + T.y;
    }
    const float u_in = eA*SB + eB;

    // ---- final back-substitution IN PLACE over drv + float4 stores ----
    float un = u_in;
    #pragma unroll
    for (int k = CH - 1; k >= 0; --k) {
        un = drv[k] - cpv[k]*un;
        drv[k] = un;
    }
    float4* o4 = reinterpret_cast<float4*>(out + (size_t)row * NN + base);
    #pragma unroll
    for (int k = 0; k < CH / 4; ++k) {
        o4[k] = make_float4(drv[4*k+0], drv[4*k+1], drv[4*k+2], drv[4*k+3]);
    }
}

extern "C" void kernel_launch(void* const* d_in, const int* in_sizes, int n_in,
                              void* d_out, int out_size, void* d_ws, size_t ws_size,
                              hipStream_t stream) {
    const float* alpha = (const float*)d_in[0];
    const float* fvec  = (const float*)d_in[1];
    float* out = (float*)d_out;
    const int nrows = out_size / NN;   // 2048
    thomas_scan_kernel<<<nrows, TB, 0, stream>>>(alpha, fvec, out);
}

// Round 3
// 157.572 us; speedup vs baseline: 1.0158x; 1.0158x over previous
//
#include <hip/hip_runtime.h>

// Batched Thomas solve, B=2048 rows, N=8192, fp32.
// One block per row; TB=1024 threads x CH=8-element contiguous chunks.
//
// R7 vs R6 (post-mortem: R6 spilled ~2 arrays to scratch -- WRITE 147MB vs
// 64MB output, FETCH +40MB, VALUBusy 37% on vmcnt stalls. Root cause: at
// launch_bounds(1024,8) the budget is 64 unified regs/wave; holding
// va+vf+cpv+drv (32 floats) ACROSS shuffle scans + scan temps exceeds it).
// Fix: move the two long-lived per-thread arrays (cpv, drv) to LDS.
//  - [CH][TB] layout: lane-contiguous addresses -> conflict-free.
//  - Thread only reads its own slots -> no extra __syncthreads.
//  - 2 x 32KiB + 512B totals = ~66KiB/block; gfx950 allows >64KiB/wg
//    (160KiB/CU) and 66KiB still fits 2 blocks/CU => 8 waves/EU kept.
//  - Register peak becomes va+vf (16) + scan state + addrs ~ 35 regs.
// Algebra identical to R6 (2x2 cp scan, affine dp scan, column prefixes).

#define NN 8192
#define TB 1024
#define CH 8           // NN / TB
#define NWAVE (TB/64)  // 16

__device__ __forceinline__ float frcp(float x) { return __builtin_amdgcn_rcpf(x); }

__global__ __launch_bounds__(TB, 8)
void thomas_scan_kernel(const float* __restrict__ alpha,
                        const float* __restrict__ fvec,
                        float* __restrict__ out)
{
    __shared__ float s_cpv[CH][TB];                 // 32 KiB: cp values
    __shared__ float s_drv[CH][TB];                 // 32 KiB: rd -> dp -> (dead)
    __shared__ __align__(16) float wtot[NWAVE][4];  // cp 2x2 wave totals (p,q,u,v)
    __shared__ __align__(8)  float dtot[NWAVE][2];  // dp affine wave totals (A,B)
    __shared__ __align__(8)  float btot[NWAVE][2];  // backward affine wave totals

    const int t    = threadIdx.x;
    const int lane = t & 63;
    const int wid  = t >> 6;
    const int row  = blockIdx.x;
    const float* __restrict__ arow = alpha + (size_t)row * NN;
    const int base = t * CH;

    // ---- load alpha chunk + halo, f chunk into registers ----
    float va[CH], vf[CH];
    {
        const float4* a4 = reinterpret_cast<const float4*>(arow + base);
        const float4* f4 = reinterpret_cast<const float4*>(fvec + base);
        #pragma unroll
        for (int k = 0; k < CH / 4; ++k) {
            float4 x = a4[k];
            va[4*k+0]=x.x; va[4*k+1]=x.y; va[4*k+2]=x.z; va[4*k+3]=x.w;
            float4 y = f4[k];
            vf[4*k+0]=y.x; vf[4*k+1]=y.y; vf[4*k+2]=y.z; vf[4*k+3]=y.w;
        }
    }
    const float aL = (t > 0)      ? arow[base - 1]  : 0.0f;  // => a_0 = 0
    const float aR = (t < TB - 1) ? arow[base + CH] : 0.0f;  // => c_{N-1} = 0

    // ---- Phase A: 2x2 cp chunk map [[p,q],[u,v]] on homogeneous (x,z) ----
    float p=1.f, q=0.f, u=0.f, v=1.f;
    #pragma unroll
    for (int k = 0; k < CH; ++k) {
        const float am1 = (k == 0)      ? aL : va[k-1];
        const float ap1 = (k == CH - 1) ? aR : va[k+1];
        const float ai = am1 * am1;
        const float bi = 1.0f + va[k]*va[k]*va[k];
        const float ci = ap1 * (ap1 + 2.0f);
        const float np = ci*u,        nq = ci*v;
        const float nu = bi*u - ai*p, nv = bi*v - ai*q;
        p=np; q=nq; u=nu; v=nv;
    }
    { const float inv = frcp(v); p*=inv; q*=inv; u*=inv; v=1.0f; }

    // ---- forward wave-inclusive shuffle scan (2x2 matmul compose) ----
    #pragma unroll
    for (int off = 1; off < 64; off <<= 1) {
        const float p1=__shfl_up(p,off), q1=__shfl_up(q,off),
                    u1=__shfl_up(u,off), v1=__shfl_up(v,off);
        if (lane >= off) {
            const float np = p*p1 + q*u1, nq = p*q1 + q*v1;
            const float nu = u*p1 + v*u1, nv = u*q1 + v*v1;
            p=np; q=nq; u=nu; v=nv;
        }
    }
    if (lane == 63) { wtot[wid][0]=p; wtot[wid][1]=q; wtot[wid][2]=u; wtot[wid][3]=v; }
    __syncthreads();

    // exclusive-within-wave map
    float ep=__shfl_up(p,1), eq=__shfl_up(q,1), eu=__shfl_up(u,1), ev=__shfl_up(v,1);
    if (lane == 0) { ep=1.f; eq=0.f; eu=0.f; ev=1.f; }

    // prefix over previous waves, COLUMN form: state = T_{w-1}..T_0 * (0,1)^T
    float Pq = 0.f, Pv = 1.f;
    for (int w = 0; w < wid; ++w) {
        const float4 T = *reinterpret_cast<const float4*>(wtot[w]);
        const float nq = T.x*Pq + T.y*Pv;
        const float nv = T.z*Pq + T.w*Pv;
        Pq = nq; Pv = nv;
    }
    float cp;
    {
        const float nx = ep*Pq + eq*Pv;
        const float nz = eu*Pq + ev*Pv;
        cp = nx * frcp(nz);
    }

    // ---- Phase C: homogeneous forward sweep; cpv and rd go to LDS ----
    // x_k = c_k z_{k-1}; z_k = b_k z_{k-1} - a_k x_{k-1};
    // y_k = f_k z_{k-1} - a_k y_{k-1};  rd_k = z_{k-1}/z_k
    float Ad, Bd;
    {
        float xp = cp, zp = 1.0f, yb = 0.0f, alp = 1.0f;
        #pragma unroll
        for (int k = 0; k < CH; ++k) {
            const float am1 = (k == 0)      ? aL : va[k-1];
            const float ap1 = (k == CH - 1) ? aR : va[k+1];
            const float ai = am1 * am1;
            const float bi = 1.0f + va[k]*va[k]*va[k];
            const float ci = ap1 * (ap1 + 2.0f);
            const float x = ci * zp;
            const float z = bi*zp - ai*xp;
            const float y = vf[k]*zp - ai*yb;
            const float rdz = frcp(z);
            s_cpv[k][t] = x  * rdz;
            s_drv[k][t] = zp * rdz;
            alp = -ai * alp;
            xp = x; zp = z; yb = y;
        }
        // dp chunk affine map from final sweep state only
        const float rdzL = frcp(zp);
        Ad = alp * rdzL;
        Bd = yb  * rdzL;
    }

    // ---- dp affine wave scan: chunk map dp_out = Ad*dp_in + Bd ----
    #pragma unroll
    for (int off = 1; off < 64; off <<= 1) {
        const float A1 = __shfl_up(Ad, off);
        const float B1 = __shfl_up(Bd, off);
        if (lane >= off) { Bd = Ad*B1 + Bd; Ad = Ad*A1; }
    }
    if (lane == 63) { dtot[wid][0]=Ad; dtot[wid][1]=Bd; }
    __syncthreads();

    float eAd = __shfl_up(Ad,1), eBd = __shfl_up(Bd,1);
    if (lane == 0) { eAd = 1.0f; eBd = 0.0f; }
    float PB = 0.f;  // prefix applied to dp_0 = 0: only B needed
    for (int w = 0; w < wid; ++w) {
        const float2 T = *reinterpret_cast<const float2*>(dtot[w]);
        PB = T.x*PB + T.y;
    }
    const float dp_in = eAd*PB + eBd;

    // ---- dp resweep IN PLACE over s_drv (rd_k read, dp_k written) ----
    {
        float dp = dp_in;
        #pragma unroll
        for (int k = 0; k < CH; ++k) {
            const float am1 = (k == 0) ? aL : va[k-1];
            const float ai  = am1 * am1;
            dp = (vf[k] - ai*dp) * s_drv[k][t];
            s_drv[k][t] = dp;
        }
    }
    // va, vf dead from here.

    // ---- Phase D: backward affine chunk map u_left = A*u_right + B ----
    float A = 1.0f, Bb = 0.0f;
    #pragma unroll
    for (int k = CH - 1; k >= 0; --k) {
        const float cpk = s_cpv[k][t];
        Bb = s_drv[k][t] - cpk*Bb;
        A  = -cpk*A;
    }
    // wave-inclusive suffix scan: comp(mine, later): B = A*B1 + B, A = A*A1
    #pragma unroll
    for (int off = 1; off < 64; off <<= 1) {
        const float A1 = __shfl_down(A, off);
        const float B1 = __shfl_down(Bb, off);
        if (lane < 64 - off) { Bb = A*B1 + Bb; A = A*A1; }
    }
    if (lane == 0) { btot[wid][0] = A; btot[wid][1] = Bb; }
    __syncthreads();

    // exclusive-within-wave suffix
    float eA = __shfl_down(A, 1), eB = __shfl_down(Bb, 1);
    if (lane == 63) { eA = 1.0f; eB = 0.0f; }
    // suffix over later waves applied to u_N = 0: only B needed
    float SB = 0.f;
    for (int w = NWAVE - 1; w > wid; --w) {
        const float2 T = *reinterpret_cast<const float2*>(btot[w]);
        SB = T.x*SB + T.y;
    }
    const float u_in = eA*SB + eB;

    // ---- final back-substitution + float4 stores ----
    float uv[CH];
    float un = u_in;
    #pragma unroll
    for (int k = CH - 1; k >= 0; --k) {
        un = s_drv[k][t] - s_cpv[k][t]*un;
        uv[k] = un;
    }
    float4* o4 = reinterpret_cast<float4*>(out + (size_t)row * NN + base);
    #pragma unroll
    for (int k = 0; k < CH / 4; ++k) {
        o4[k] = make_float4(uv[4*k+0], uv[4*k+1], uv[4*k+2], uv[4*k+3]);
    }
}

extern "C" void kernel_launch(void* const* d_in, const int* in_sizes, int n_in,
                              void* d_out, int out_size, void* d_ws, size_t ws_size,
                              hipStream_t stream) {
    const float* alpha = (const float*)d_in[0];
    const float* fvec  = (const float*)d_in[1];
    float* out = (float*)d_out;
    const int nrows = out_size / NN;   // 2048
    thomas_scan_kernel<<<nrows, TB, 0, stream>>>(alpha, fvec, out);
}

// Round 4
// 136.135 us; speedup vs baseline: 1.1757x; 1.1575x over previous
//
#include <hip/hip_runtime.h>

// Batched Thomas solve, B=2048 rows, N=8192, fp32.
// One block per row; TB=1024 threads x CH=8-element contiguous chunks.
//
// R8 vs R7 (post-mortem: STILL one 8-float array spilled -- WRITE 128MiB =
// output + exactly 64MiB, FETCH +26MB of L2-cached spill re-reads. va/vf/uv
// register arrays live across 3 shuffle scans + 2 barriers exceed the 64
// unified regs that launch_bounds(1024,8) allows; allocator spills instead
// of shrinking scan temps. With 16-wave blocks the only occupancy points are
// 64 regs (2 blk/CU, 8 w/EU) or 128 regs (1 blk/CU, 4 w/EU) -- we need 64.)
// Fix: NO persistent register arrays anywhere.
//  - cpv, rd->dp stay in LDS (64 KiB, conflict-free, 2 blocks/CU kept).
//  - va/vf are RE-LOADED from global in phase-scoped arrays (live range ends
//    at phase boundary). alpha row (32KiB/blk) + f (32KiB, shared) are L2/L3
//    resident across re-reads; ~4 extra float4 L2-hit loads/thread, hidden.
//  - tail uv[] removed: back-sub stores in two float4 groups as produced.
// Peak live set per phase ~ 30 regs. Algebra identical to R6/R7.

#define NN 8192
#define TB 1024
#define CH 8           // NN / TB
#define NWAVE (TB/64)  // 16

__device__ __forceinline__ float frcp(float x) { return __builtin_amdgcn_rcpf(x); }

__global__ __launch_bounds__(TB, 8)
void thomas_scan_kernel(const float* __restrict__ alpha,
                        const float* __restrict__ fvec,
                        float* __restrict__ out)
{
    __shared__ float s_cpv[CH][TB];                 // 32 KiB: cp values
    __shared__ float s_drv[CH][TB];                 // 32 KiB: rd -> dp
    __shared__ __align__(16) float wtot[NWAVE][4];  // cp 2x2 wave totals
    __shared__ __align__(8)  float dtot[NWAVE][2];  // dp affine wave totals
    __shared__ __align__(8)  float btot[NWAVE][2];  // backward affine totals

    const int t    = threadIdx.x;
    const int lane = t & 63;
    const int wid  = t >> 6;
    const int row  = blockIdx.x;
    const float* __restrict__ arow = alpha + (size_t)row * NN;
    const int base = t * CH;

    const float aL = (t > 0)      ? arow[base - 1]  : 0.0f;  // => a_0 = 0
    const float aR = (t < TB - 1) ? arow[base + CH] : 0.0f;  // => c_{N-1} = 0

    // ---- Phase A: 2x2 cp chunk map [[p,q],[u,v]] on homogeneous (x,z) ----
    float p=1.f, q=0.f, u=0.f, v=1.f;
    {
        float va[CH];  // phase-scoped
        const float4* a4 = reinterpret_cast<const float4*>(arow + base);
        const float4 x0 = a4[0], x1 = a4[1];
        va[0]=x0.x; va[1]=x0.y; va[2]=x0.z; va[3]=x0.w;
        va[4]=x1.x; va[5]=x1.y; va[6]=x1.z; va[7]=x1.w;
        #pragma unroll
        for (int k = 0; k < CH; ++k) {
            const float am1 = (k == 0)      ? aL : va[k-1];
            const float ap1 = (k == CH - 1) ? aR : va[k+1];
            const float ai = am1 * am1;
            const float bi = 1.0f + va[k]*va[k]*va[k];
            const float ci = ap1 * (ap1 + 2.0f);
            const float np = ci*u,        nq = ci*v;
            const float nu = bi*u - ai*p, nv = bi*v - ai*q;
            p=np; q=nq; u=nu; v=nv;
        }
        const float inv = frcp(v); p*=inv; q*=inv; u*=inv; v=1.0f;
    }

    // ---- forward wave-inclusive shuffle scan (2x2 matmul compose) ----
    #pragma unroll
    for (int off = 1; off < 64; off <<= 1) {
        const float p1=__shfl_up(p,off), q1=__shfl_up(q,off),
                    u1=__shfl_up(u,off), v1=__shfl_up(v,off);
        if (lane >= off) {
            const float np = p*p1 + q*u1, nq = p*q1 + q*v1;
            const float nu = u*p1 + v*u1, nv = u*q1 + v*v1;
            p=np; q=nq; u=nu; v=nv;
        }
    }
    if (lane == 63) { wtot[wid][0]=p; wtot[wid][1]=q; wtot[wid][2]=u; wtot[wid][3]=v; }
    __syncthreads();

    // exclusive-within-wave map
    float ep=__shfl_up(p,1), eq=__shfl_up(q,1), eu=__shfl_up(u,1), ev=__shfl_up(v,1);
    if (lane == 0) { ep=1.f; eq=0.f; eu=0.f; ev=1.f; }

    // prefix over previous waves, COLUMN form: state = T_{w-1}..T_0 * (0,1)^T
    float Pq = 0.f, Pv = 1.f;
    for (int w = 0; w < wid; ++w) {
        const float4 T = *reinterpret_cast<const float4*>(wtot[w]);
        const float nq = T.x*Pq + T.y*Pv;
        const float nv = T.z*Pq + T.w*Pv;
        Pq = nq; Pv = nv;
    }
    float cp;
    {
        const float nx = ep*Pq + eq*Pv;
        const float nz = eu*Pq + ev*Pv;
        cp = nx * frcp(nz);
    }

    // ---- Phase C: homogeneous forward sweep; cpv and rd into LDS ----
    float Ad, Bd;
    {
        float va[CH], vf[CH];  // phase-scoped reload (L2-hot)
        const float4* a4 = reinterpret_cast<const float4*>(arow + base);
        const float4* f4 = reinterpret_cast<const float4*>(fvec + base);
        const float4 x0 = a4[0], x1 = a4[1];
        const float4 y0 = f4[0], y1 = f4[1];
        va[0]=x0.x; va[1]=x0.y; va[2]=x0.z; va[3]=x0.w;
        va[4]=x1.x; va[5]=x1.y; va[6]=x1.z; va[7]=x1.w;
        vf[0]=y0.x; vf[1]=y0.y; vf[2]=y0.z; vf[3]=y0.w;
        vf[4]=y1.x; vf[5]=y1.y; vf[6]=y1.z; vf[7]=y1.w;

        float xp = cp, zp = 1.0f, yb = 0.0f, alp = 1.0f;
        #pragma unroll
        for (int k = 0; k < CH; ++k) {
            const float am1 = (k == 0)      ? aL : va[k-1];
            const float ap1 = (k == CH - 1) ? aR : va[k+1];
            const float ai = am1 * am1;
            const float bi = 1.0f + va[k]*va[k]*va[k];
            const float ci = ap1 * (ap1 + 2.0f);
            const float x = ci * zp;
            const float z = bi*zp - ai*xp;
            const float y = vf[k]*zp - ai*yb;
            const float rdz = frcp(z);
            s_cpv[k][t] = x  * rdz;
            s_drv[k][t] = zp * rdz;
            alp = -ai * alp;
            xp = x; zp = z; yb = y;
        }
        const float rdzL = frcp(zp);
        Ad = alp * rdzL;
        Bd = yb  * rdzL;
    }

    // ---- dp affine wave scan: chunk map dp_out = Ad*dp_in + Bd ----
    #pragma unroll
    for (int off = 1; off < 64; off <<= 1) {
        const float A1 = __shfl_up(Ad, off);
        const float B1 = __shfl_up(Bd, off);
        if (lane >= off) { Bd = Ad*B1 + Bd; Ad = Ad*A1; }
    }
    if (lane == 63) { dtot[wid][0]=Ad; dtot[wid][1]=Bd; }
    __syncthreads();

    float eAd = __shfl_up(Ad,1), eBd = __shfl_up(Bd,1);
    if (lane == 0) { eAd = 1.0f; eBd = 0.0f; }
    float PB = 0.f;  // prefix applied to dp_0 = 0: only B needed
    for (int w = 0; w < wid; ++w) {
        const float2 T = *reinterpret_cast<const float2*>(dtot[w]);
        PB = T.x*PB + T.y;
    }
    const float dp_in = eAd*PB + eBd;

    // ---- dp resweep IN PLACE over s_drv (rd_k read, dp_k written) ----
    {
        float va[CH], vf[CH];  // phase-scoped reload (L2-hot)
        const float4* a4 = reinterpret_cast<const float4*>(arow + base);
        const float4* f4 = reinterpret_cast<const float4*>(fvec + base);
        const float4 x0 = a4[0], x1 = a4[1];
        const float4 y0 = f4[0], y1 = f4[1];
        va[0]=x0.x; va[1]=x0.y; va[2]=x0.z; va[3]=x0.w;
        va[4]=x1.x; va[5]=x1.y; va[6]=x1.z; va[7]=x1.w;
        vf[0]=y0.x; vf[1]=y0.y; vf[2]=y0.z; vf[3]=y0.w;
        vf[4]=y1.x; vf[5]=y1.y; vf[6]=y1.z; vf[7]=y1.w;

        float dp = dp_in;
        #pragma unroll
        for (int k = 0; k < CH; ++k) {
            const float am1 = (k == 0) ? aL : va[k-1];
            const float ai  = am1 * am1;
            dp = (vf[k] - ai*dp) * s_drv[k][t];
            s_drv[k][t] = dp;
        }
    }

    // ---- Phase D: backward affine chunk map u_left = A*u_right + B ----
    float A = 1.0f, Bb = 0.0f;
    #pragma unroll
    for (int k = CH - 1; k >= 0; --k) {
        const float cpk = s_cpv[k][t];
        Bb = s_drv[k][t] - cpk*Bb;
        A  = -cpk*A;
    }
    // wave-inclusive suffix scan: comp(mine, later): B = A*B1 + B, A = A*A1
    #pragma unroll
    for (int off = 1; off < 64; off <<= 1) {
        const float A1 = __shfl_down(A, off);
        const float B1 = __shfl_down(Bb, off);
        if (lane < 64 - off) { Bb = A*B1 + Bb; A = A*A1; }
    }
    if (lane == 0) { btot[wid][0] = A; btot[wid][1] = Bb; }
    __syncthreads();

    // exclusive-within-wave suffix
    float eA = __shfl_down(A, 1), eB = __shfl_down(Bb, 1);
    if (lane == 63) { eA = 1.0f; eB = 0.0f; }
    // suffix over later waves applied to u_N = 0: only B needed
    float SB = 0.f;
    for (int w = NWAVE - 1; w > wid; --w) {
        const float2 T = *reinterpret_cast<const float2*>(btot[w]);
        SB = T.x*SB + T.y;
    }
    const float u_in = eA*SB + eB;

    // ---- final back-substitution, store as two float4 groups ----
    float4* o4 = reinterpret_cast<float4*>(out + (size_t)row * NN + base);
    float un = u_in;
    {
        float u7, u6, u5, u4;
        un = s_drv[7][t] - s_cpv[7][t]*un; u7 = un;
        un = s_drv[6][t] - s_cpv[6][t]*un; u6 = un;
        un = s_drv[5][t] - s_cpv[5][t]*un; u5 = un;
        un = s_drv[4][t] - s_cpv[4][t]*un; u4 = un;
        o4[1] = make_float4(u4, u5, u6, u7);
    }
    {
        float u3, u2, u1, u0;
        un = s_drv[3][t] - s_cpv[3][t]*un; u3 = un;
        un = s_drv[2][t] - s_cpv[2][t]*un; u2 = un;
        un = s_drv[1][t] - s_cpv[1][t]*un; u1 = un;
        un = s_drv[0][t] - s_cpv[0][t]*un; u0 = un;
        o4[0] = make_float4(u0, u1, u2, u3);
    }
}

extern "C" void kernel_launch(void* const* d_in, const int* in_sizes, int n_in,
                              void* d_out, int out_size, void* d_ws, size_t ws_size,
                              hipStream_t stream) {
    const float* alpha = (const float*)d_in[0];
    const float* fvec  = (const float*)d_in[1];
    float* out = (float*)d_out;
    const int nrows = out_size / NN;   // 2048
    thomas_scan_kernel<<<nrows, TB, 0, stream>>>(alpha, fvec, out);
}